// Round 22
// baseline (140.226 us; speedup 1.0000x reference)
//
#include <hip/hip_runtime.h>

#define BB 16
#define NN 4096
#define EE 65536
#define HH 512
#define M1N 1024
#define M2N 32768
#define CAP 96

typedef unsigned short ushortT;
typedef short   s8v   __attribute__((ext_vector_type(8)));   // 8 bf16 (4 VGPRs)
typedef float   f4v   __attribute__((ext_vector_type(4)));

__device__ inline ushortT f2b(float x) {       // f32 -> bf16 bits, RNE
  unsigned u = __float_as_uint(x);
  return (ushortT)((u + 0x7FFFu + ((u >> 16) & 1u)) >> 16);
}

// Layouts: as*/ad* [NN][16] f32; h0t/h1t [NN][16][32] f32 (batch innermost).
// o1b = bf16 o1 [16][1024]; lin2 weights converted f32->bf16 in-register.
// k_big: lin2m and agg0 blocks INTERLEAVED by bid parity so both kinds are
// co-resident (r11's sequential-range merge serialized on the dispatcher).
// 4 launches: pre{zero|gru|h0proj} mid1{lin1|fill} big{lin2m(+)agg0} fin

// ============ L1: {zero cnt | GRU | GAT0 h-projection} ========================

__global__ void k_pre(int* __restrict__ cnt,
                      const float* __restrict__ x, const float* __restrict__ hid,
                      const float* __restrict__ w_ih, const float* __restrict__ w_hh,
                      const float* __restrict__ b_ih, const float* __restrict__ b_hh,
                      float* __restrict__ nh, float* __restrict__ out_nh,
                      const float* __restrict__ svp, const float* __restrict__ W0,
                      const float* __restrict__ a0s, const float* __restrict__ a0d,
                      float* __restrict__ h0t, float* __restrict__ as0t,
                      float* __restrict__ ad0t) {
  const int bid = blockIdx.x;
  if (bid < 16) {                     // zero the per-node fill counters (4096)
    cnt[bid * 256 + threadIdx.x] = 0;
    return;
  }
  if (bid < 2064) {                   // GRU: wave per (b,j)
    int wid = (bid - 16) * 4 + (threadIdx.x >> 6);
    int lane = threadIdx.x & 63;
    int b = wid >> 9, j = wid & 511;
    const float* xb = x + b * 256;
    const float* hb = hid + b * HH;
    float ir = 0.f, iz = 0.f, in_ = 0.f, hr = 0.f, hz = 0.f, hn = 0.f;
    for (int k = lane; k < 256; k += 64) {
      float xv = xb[k];
      ir  += xv * w_ih[(size_t)j * 256 + k];
      iz  += xv * w_ih[(size_t)(j + 512) * 256 + k];
      in_ += xv * w_ih[(size_t)(j + 1024) * 256 + k];
    }
    for (int k = lane; k < 512; k += 64) {
      float hv = hb[k];
      hr += hv * w_hh[(size_t)j * 512 + k];
      hz += hv * w_hh[(size_t)(j + 512) * 512 + k];
      hn += hv * w_hh[(size_t)(j + 1024) * 512 + k];
    }
#pragma unroll
    for (int m = 1; m < 64; m <<= 1) {
      ir += __shfl_xor(ir, m, 64); iz += __shfl_xor(iz, m, 64); in_ += __shfl_xor(in_, m, 64);
      hr += __shfl_xor(hr, m, 64); hz += __shfl_xor(hz, m, 64); hn  += __shfl_xor(hn, m, 64);
    }
    if (lane == 0) {
      ir += b_ih[j]; iz += b_ih[j + 512]; in_ += b_ih[j + 1024];
      hr += b_hh[j]; hz += b_hh[j + 512]; hn += b_hh[j + 1024];
      float r = 1.f / (1.f + __expf(-(ir + hr)));
      float z = 1.f / (1.f + __expf(-(iz + hz)));
      float n = tanhf(in_ + r * hn);
      float v = (1.f - z) * n + z * hb[j];
      nh[wid] = v;
      out_nh[wid] = v;
    }
    return;
  }
  // GAT0 projection (FIN=3), transposed outputs
  int gid = (bid - 2064) * 256 + threadIdx.x;
  int grp = gid >> 5, f = gid & 31;          // grp = b*N + n
  int b = grp >> 12, n = grp & 4095;
  const float* v = svp + (size_t)grp * 3;
  float hv = v[0] * W0[f * 3] + v[1] * W0[f * 3 + 1] + v[2] * W0[f * 3 + 2];
  h0t[(size_t)n * 512 + b * 32 + f] = hv;
  float ps = hv * a0s[f], pd = hv * a0d[f];
#pragma unroll
  for (int m = 1; m < 32; m <<= 1) {         // reduce within each 32-lane half
    ps += __shfl_xor(ps, m, 64);
    pd += __shfl_xor(pd, m, 64);
  }
  if (f == 0) { as0t[n * 16 + b] = ps; ad0t[n * 16 + b] = pd; }
}

// ============ L2: {lin1 -> o1b | padded-CSR fill} =============================

__global__ void k_mid1(const float* __restrict__ nh, const float* __restrict__ l1w,
                       const float* __restrict__ l1b, const float* __restrict__ p1,
                       const float* __restrict__ g1v, const float* __restrict__ be1,
                       ushortT* __restrict__ o1b,
                       const int* __restrict__ src, const int* __restrict__ dst,
                       int* __restrict__ cnt, int* __restrict__ csr) {
  const int bid = blockIdx.x;
  if (bid < 4096) {                   // lin1: wave per (b,j); bf16 output
    const int wave = threadIdx.x >> 6;
    const int lane = threadIdx.x & 63;
    int wid = bid * 4 + wave;
    int b = wid >> 10, j = wid & 1023;
    const float* hb = nh + b * HH;
    const float* wr = l1w + (size_t)j * HH;
    float acc = 0.f;
    for (int k = lane; k < HH; k += 64) acc += hb[k] * wr[k];
#pragma unroll
    for (int m = 1; m < 64; m <<= 1) acc += __shfl_xor(acc, m, 64);
    if (lane == 0) {
      float t = acc + l1b[j];
      t = t >= 0.f ? t : p1[j] * t;
      o1b[wid] = f2b(t * 0.99999500003749973f * g1v[j] + be1[j]);
    }
    return;
  }
  // padded-CSR direct fill
  int k = (bid - 4096) * 256 + threadIdx.x;
  if (k < EE) {
    int d = dst[k];
    int slot = atomicAdd(&cnt[d], 1);
    if ((unsigned)slot < CAP) csr[d * CAP + slot] = src[k];
  }
}

// ============ L3: {lin2m MFMA | agg0 + h1-projection}, parity-interleaved =====
// Even bid -> lin2m tile (bid>>1); odd bid -> agg0 node-pair (bid>>1). Both
// block kinds co-resident from dispatch 0: the L2-latency-bound gather hides
// under the LLC/HBM weight stream's memory stalls (different pipes).

__global__ __launch_bounds__(256) void k_big(
    const ushortT* __restrict__ o1b, const float* __restrict__ l2w,
    const float* __restrict__ l2b, const float* __restrict__ p2,
    const float* __restrict__ g2v, const float* __restrict__ be2,
    float* __restrict__ o2,
    const int* __restrict__ cnt, const int* __restrict__ csr,
    const float* __restrict__ h0t, const float* __restrict__ as0t,
    const float* __restrict__ ad0t, const float* __restrict__ b0,
    const float* __restrict__ W1, const float* __restrict__ a1s,
    const float* __restrict__ a1d,
    float* __restrict__ h1t, float* __restrict__ as1t,
    float* __restrict__ ad1t) {
  const int bid = blockIdx.x;
  const int wave = threadIdx.x >> 6;
  const int lane = threadIdx.x & 63;
  __shared__ union {
    f4v p[4][64];                     // lin2m partials
    float g[4][8][36];                // agg0 broadcast
  } sh;
  if ((bid & 1) == 0) {               // ---- lin2m: one 16-col tile, K-split 4x
    const int r16 = lane & 15;
    const int chunk = lane >> 4;
    const int j0 = (bid >> 1) * 16;
    const int kbase = wave * 256 + chunk * 8;
    const s8v* ap = (const s8v*)(o1b + r16 * 1024 + kbase);
    const f4v* bp = (const f4v*)(l2w + (size_t)(j0 + r16) * 1024 + kbase);
    f4v acc = {0.f, 0.f, 0.f, 0.f};
#pragma unroll
    for (int it = 0; it < 8; ++it) {
      s8v a = ap[it * 4];
      f4v w0 = bp[it * 8];
      f4v w1 = bp[it * 8 + 1];
      s8v b;
      b[0] = (short)f2b(w0[0]); b[1] = (short)f2b(w0[1]);
      b[2] = (short)f2b(w0[2]); b[3] = (short)f2b(w0[3]);
      b[4] = (short)f2b(w1[0]); b[5] = (short)f2b(w1[1]);
      b[6] = (short)f2b(w1[2]); b[7] = (short)f2b(w1[3]);
      acc = __builtin_amdgcn_mfma_f32_16x16x32_bf16(a, b, acc, 0, 0, 0);
    }
    sh.p[wave][lane] = acc;
    __syncthreads();
    if (wave == 0) {
      f4v s = sh.p[0][lane] + sh.p[1][lane] + sh.p[2][lane] + sh.p[3][lane];
      const int j = j0 + r16;
      const float bj = l2b[j], pj = p2[j], gj = g2v[j], bej = be2[j];
      const float INV = 0.99999500003749973f;
#pragma unroll
      for (int r = 0; r < 4; ++r) {
        int b = chunk * 4 + r;        // batch row
        float t = s[r] + bj;
        t = t >= 0.f ? t : pj * t;
        o2[(size_t)b * M2N + j] = t * INV * gj + bej;
      }
    }
    return;
  }
  // ---- agg0 + h1 projection: 2 nodes per block
  const int n  = (bid >> 1) * 2 + (wave >> 1);
  const int bh = wave & 1;
  const int bl = lane >> 3;
  const int fq = lane & 7;
  const int b  = bh * 8 + bl;
  const int f0 = fq * 4;
  const int boff = b * 32 + f0;
  const int deg = min(cnt[n], CAP);
  const int base = n * CAP;
  const float adn = ad0t[n * 16 + b];
  const int total = deg + 1;          // + self loop
  float4 acc = {0.f, 0.f, 0.f, 0.f};
  float asum = 0.f;
  for (int i = 0; i < total; i += 4) {
    int r0 = csr[base + i];
    int r1 = csr[base + i + 1];
    int r2 = csr[base + i + 2];
    int r3 = csr[base + i + 3];
    int sv0 = (i     < deg) ? r0 : n;
    int sv1 = (i + 1 < deg) ? r1 : n;
    int sv2 = (i + 2 < deg) ? r2 : n;
    int sv3 = (i + 3 < deg) ? r3 : n;
    float e0 = as0t[sv0 * 16 + b];
    float e1 = as0t[sv1 * 16 + b];
    float e2 = as0t[sv2 * 16 + b];
    float e3 = as0t[sv3 * 16 + b];
    float4 hv0 = *(const float4*)(h0t + (size_t)sv0 * 512 + boff);
    float4 hv1 = *(const float4*)(h0t + (size_t)sv1 * 512 + boff);
    float4 hv2 = *(const float4*)(h0t + (size_t)sv2 * 512 + boff);
    float4 hv3 = *(const float4*)(h0t + (size_t)sv3 * 512 + boff);
    float e, w;
    e = e0 + adn; e = e >= 0.f ? e : 0.2f * e;
    w = (i     < total) ? __expf(e) : 0.f;
    asum += w; acc.x += w*hv0.x; acc.y += w*hv0.y; acc.z += w*hv0.z; acc.w += w*hv0.w;
    e = e1 + adn; e = e >= 0.f ? e : 0.2f * e;
    w = (i + 1 < total) ? __expf(e) : 0.f;
    asum += w; acc.x += w*hv1.x; acc.y += w*hv1.y; acc.z += w*hv1.z; acc.w += w*hv1.w;
    e = e2 + adn; e = e >= 0.f ? e : 0.2f * e;
    w = (i + 2 < total) ? __expf(e) : 0.f;
    asum += w; acc.x += w*hv2.x; acc.y += w*hv2.y; acc.z += w*hv2.z; acc.w += w*hv2.w;
    e = e3 + adn; e = e >= 0.f ? e : 0.2f * e;
    w = (i + 3 < total) ? __expf(e) : 0.f;
    asum += w; acc.x += w*hv3.x; acc.y += w*hv3.y; acc.z += w*hv3.z; acc.w += w*hv3.w;
  }
  float inv = 1.f / asum;
  float4 b0v = *(const float4*)(b0 + f0);
  float4 g0;
  g0.x = acc.x * inv + b0v.x; g0.y = acc.y * inv + b0v.y;
  g0.z = acc.z * inv + b0v.z; g0.w = acc.w * inv + b0v.w;
  *(float4*)&sh.g[wave][bl][f0] = g0;
  __syncthreads();
  float h1a = 0.f, h1b = 0.f, h1c = 0.f, h1d = 0.f;
  const float* gr = sh.g[wave][bl];
  const float* w1r = W1 + f0 * 32;
#pragma unroll
  for (int k = 0; k < 32; ++k) {
    float gk = gr[k];
    h1a += gk * w1r[k];
    h1b += gk * w1r[32 + k];
    h1c += gk * w1r[64 + k];
    h1d += gk * w1r[96 + k];
  }
  float4 h1v = {h1a, h1b, h1c, h1d};
  *(float4*)(h1t + (size_t)n * 512 + boff) = h1v;
  float ps = h1a * a1s[f0] + h1b * a1s[f0+1] + h1c * a1s[f0+2] + h1d * a1s[f0+3];
  float pd = h1a * a1d[f0] + h1b * a1d[f0+1] + h1c * a1d[f0+2] + h1d * a1d[f0+3];
#pragma unroll
  for (int m = 1; m < 8; m <<= 1) {                 // reduce over the 8 fq lanes
    ps += __shfl_xor(ps, m, 64);
    pd += __shfl_xor(pd, m, 64);
  }
  if (fq == 0) { as1t[n * 16 + b] = ps; ad1t[n * 16 + b] = pd; }
}

// ============ L4: agg1 + fused output projection ==============================

__global__ void k_fin(const int* __restrict__ cnt, const int* __restrict__ csr,
                      const float* __restrict__ h1t, const float* __restrict__ as1t,
                      const float* __restrict__ ad1t, const float* __restrict__ b1,
                      const float* __restrict__ o2, const float* __restrict__ wout,
                      const float* __restrict__ bout, float* __restrict__ y) {
  const int wave = threadIdx.x >> 6;
  const int lane = threadIdx.x & 63;
  const int n  = blockIdx.x * 2 + (wave >> 1);
  const int bh = wave & 1;
  const int bl = lane >> 3;
  const int fq = lane & 7;
  const int b  = bh * 8 + bl;
  const int f0 = fq * 4;
  const int boff = b * 32 + f0;
  const int deg = min(cnt[n], CAP);
  const int base = n * CAP;
  const float adn = ad1t[n * 16 + b];
  const int total = deg + 1;
  float4 acc = {0.f, 0.f, 0.f, 0.f};
  float asum = 0.f;
  for (int i = 0; i < total; i += 4) {
    int r0 = csr[base + i];
    int r1 = csr[base + i + 1];
    int r2 = csr[base + i + 2];
    int r3 = csr[base + i + 3];
    int sv0 = (i     < deg) ? r0 : n;
    int sv1 = (i + 1 < deg) ? r1 : n;
    int sv2 = (i + 2 < deg) ? r2 : n;
    int sv3 = (i + 3 < deg) ? r3 : n;
    float e0 = as1t[sv0 * 16 + b];
    float e1 = as1t[sv1 * 16 + b];
    float e2 = as1t[sv2 * 16 + b];
    float e3 = as1t[sv3 * 16 + b];
    float4 hv0 = *(const float4*)(h1t + (size_t)sv0 * 512 + boff);
    float4 hv1 = *(const float4*)(h1t + (size_t)sv1 * 512 + boff);
    float4 hv2 = *(const float4*)(h1t + (size_t)sv2 * 512 + boff);
    float4 hv3 = *(const float4*)(h1t + (size_t)sv3 * 512 + boff);
    float e, w;
    e = e0 + adn; e = e >= 0.f ? e : 0.2f * e;
    w = (i     < total) ? __expf(e) : 0.f;
    asum += w; acc.x += w*hv0.x; acc.y += w*hv0.y; acc.z += w*hv0.z; acc.w += w*hv0.w;
    e = e1 + adn; e = e >= 0.f ? e : 0.2f * e;
    w = (i + 1 < total) ? __expf(e) : 0.f;
    asum += w; acc.x += w*hv1.x; acc.y += w*hv1.y; acc.z += w*hv1.z; acc.w += w*hv1.w;
    e = e2 + adn; e = e >= 0.f ? e : 0.2f * e;
    w = (i + 2 < total) ? __expf(e) : 0.f;
    asum += w; acc.x += w*hv2.x; acc.y += w*hv2.y; acc.z += w*hv2.z; acc.w += w*hv2.w;
    e = e3 + adn; e = e >= 0.f ? e : 0.2f * e;
    w = (i + 3 < total) ? __expf(e) : 0.f;
    asum += w; acc.x += w*hv3.x; acc.y += w*hv3.y; acc.z += w*hv3.z; acc.w += w*hv3.w;
  }
  float inv = 1.f / asum;
  float4 b1v = *(const float4*)(b1 + f0);
  float gx = acc.x * inv + b1v.x, gy = acc.y * inv + b1v.y;
  float gz = acc.z * inv + b1v.z, gw = acc.w * inv + b1v.w;
  float pc0 = gx*wout[ 8+f0] + gy*wout[ 9+f0] + gz*wout[10+f0] + gw*wout[11+f0];
  float pc1 = gx*wout[48+f0] + gy*wout[49+f0] + gz*wout[50+f0] + gw*wout[51+f0];
  float pc2 = gx*wout[88+f0] + gy*wout[89+f0] + gz*wout[90+f0] + gw*wout[91+f0];
#pragma unroll
  for (int m = 1; m < 8; m <<= 1) {
    pc0 += __shfl_xor(pc0, m, 64);
    pc1 += __shfl_xor(pc1, m, 64);
    pc2 += __shfl_xor(pc2, m, 64);
  }
  if (fq == 0) {
    const float* gr = o2 + (size_t)b * M2N + n * 8;
    float4 ga = *(const float4*)gr;
    float4 gb = *(const float4*)(gr + 4);
    float c0 = pc0 + bout[0], c1 = pc1 + bout[1], c2 = pc2 + bout[2];
    c0 += ga.x*wout[0]  + ga.y*wout[1]  + ga.z*wout[2]  + ga.w*wout[3]
        + gb.x*wout[4]  + gb.y*wout[5]  + gb.z*wout[6]  + gb.w*wout[7];
    c1 += ga.x*wout[40] + ga.y*wout[41] + ga.z*wout[42] + ga.w*wout[43]
        + gb.x*wout[44] + gb.y*wout[45] + gb.z*wout[46] + gb.w*wout[47];
    c2 += ga.x*wout[80] + ga.y*wout[81] + ga.z*wout[82] + ga.w*wout[83]
        + gb.x*wout[84] + gb.y*wout[85] + gb.z*wout[86] + gb.w*wout[87];
    float* yp = y + (size_t)b * (NN * 3) + n * 3;
    yp[0] = c0; yp[1] = c1; yp[2] = c2;
  }
}

// ------------------------------------------------------------------------------

extern "C" void kernel_launch(void* const* d_in, const int* in_sizes, int n_in,
                              void* d_out, int out_size, void* d_ws, size_t ws_size,
                              hipStream_t stream) {
  const float* x    = (const float*)d_in[0];
  const float* svp  = (const float*)d_in[1];
  const float* hid  = (const float*)d_in[2];
  const int*   ei   = (const int*)d_in[3];
  const float* W0   = (const float*)d_in[4];
  const float* a0s  = (const float*)d_in[5];
  const float* a0d  = (const float*)d_in[6];
  const float* b0   = (const float*)d_in[7];
  const float* W1   = (const float*)d_in[8];
  const float* a1s  = (const float*)d_in[9];
  const float* a1d  = (const float*)d_in[10];
  const float* b1   = (const float*)d_in[11];
  const float* w_ih = (const float*)d_in[12];
  const float* w_hh = (const float*)d_in[13];
  const float* b_ih = (const float*)d_in[14];
  const float* b_hh = (const float*)d_in[15];
  const float* l1w  = (const float*)d_in[16];
  const float* l1b  = (const float*)d_in[17];
  const float* p1   = (const float*)d_in[18];
  const float* g1v  = (const float*)d_in[19];
  const float* be1  = (const float*)d_in[20];
  const float* l2w  = (const float*)d_in[21];
  const float* l2b  = (const float*)d_in[22];
  const float* p2   = (const float*)d_in[23];
  const float* g2v  = (const float*)d_in[24];
  const float* be2  = (const float*)d_in[25];
  const float* wout = (const float*)d_in[26];
  const float* bout = (const float*)d_in[27];
  float* out = (float*)d_out;

  char* ws = (char*)d_ws;
  size_t off = 0;
  auto alloc = [&](size_t bytes) -> char* {
    char* p = ws + off;
    off += (bytes + 255) & ~(size_t)255;
    return p;
  };
  int*     cnt   = (int*)alloc((size_t)NN * 4);
  int*     csr   = (int*)alloc(((size_t)NN * CAP + 16) * 4);  // +16 pad
  float*   h0t   = (float*)alloc((size_t)NN * 16 * 32 * 4);
  float*   as0t  = (float*)alloc((size_t)NN * 16 * 4);
  float*   ad0t  = (float*)alloc((size_t)NN * 16 * 4);
  float*   h1t   = (float*)alloc((size_t)NN * 16 * 32 * 4);
  float*   as1t  = (float*)alloc((size_t)NN * 16 * 4);
  float*   ad1t  = (float*)alloc((size_t)NN * 16 * 4);
  float*   nh    = (float*)alloc((size_t)BB * HH * 4);
  ushortT* o1b   = (ushortT*)alloc((size_t)BB * M1N * 2);
  float*   o2    = (float*)alloc((size_t)BB * M2N * 4);

  const int* srcv = ei;
  const int* dstv = ei + EE;

  k_pre<<<16 + 2048 + 8192, 256, 0, stream>>>(
      cnt, x, hid, w_ih, w_hh, b_ih, b_hh, nh, out + (size_t)BB * NN * 3,
      svp, W0, a0s, a0d, h0t, as0t, ad0t);
  k_mid1<<<4096 + 256, 256, 0, stream>>>(
      nh, l1w, l1b, p1, g1v, be1, o1b, srcv, dstv, cnt, csr);
  k_big<<<4096, 256, 0, stream>>>(
      o1b, l2w, l2b, p2, g2v, be2, o2,
      cnt, csr, h0t, as0t, ad0t, b0, W1, a1s, a1d, h1t, as1t, ad1t);
  k_fin<<<2048, 256, 0, stream>>>(cnt, csr, h1t, as1t, ad1t, b1, o2, wout, bout, out);
}

// Round 23
// 115.720 us; speedup vs baseline: 1.2118x; 1.2118x over previous
//
#include <hip/hip_runtime.h>

#define BB 16
#define NN 4096
#define EE 65536
#define HH 512
#define M1N 1024
#define M2N 32768
#define CAP 96

typedef unsigned short ushortT;
typedef short   s8v   __attribute__((ext_vector_type(8)));   // 8 bf16 (4 VGPRs)
typedef float   f4v   __attribute__((ext_vector_type(4)));

__device__ inline ushortT f2b(float x) {       // f32 -> bf16 bits, RNE
  unsigned u = __float_as_uint(x);
  return (ushortT)((u + 0x7FFFu + ((u >> 16) & 1u)) >> 16);
}

// REVERT to r17 (ledger-best, 115.8us): lin2 via MFMA with in-register
// f32->bf16 weight conversion. Eight lin2 alternatives all fell at ~2.2-2.5
// TB/s on the LLC-resident weight stream (f32 dot x4, LDS-stage, prefetch,
// deep-pipe[spill], staged-conv, K-split, NT[slower], interleave[slower]).
// 5 launches: pre{zero|gru|h0proj} fill mid{agg0+h1|lin1->o1b} lin2m fin

// ============ L1: {zero cnt | GRU | GAT0 h-projection} ========================

__global__ void k_pre(int* __restrict__ cnt,
                      const float* __restrict__ x, const float* __restrict__ hid,
                      const float* __restrict__ w_ih, const float* __restrict__ w_hh,
                      const float* __restrict__ b_ih, const float* __restrict__ b_hh,
                      float* __restrict__ nh, float* __restrict__ out_nh,
                      const float* __restrict__ svp, const float* __restrict__ W0,
                      const float* __restrict__ a0s, const float* __restrict__ a0d,
                      float* __restrict__ h0t, float* __restrict__ as0t,
                      float* __restrict__ ad0t) {
  const int bid = blockIdx.x;
  if (bid < 16) {                     // zero the per-node fill counters (4096)
    cnt[bid * 256 + threadIdx.x] = 0;
    return;
  }
  if (bid < 2064) {                   // GRU: wave per (b,j)
    int wid = (bid - 16) * 4 + (threadIdx.x >> 6);
    int lane = threadIdx.x & 63;
    int b = wid >> 9, j = wid & 511;
    const float* xb = x + b * 256;
    const float* hb = hid + b * HH;
    float ir = 0.f, iz = 0.f, in_ = 0.f, hr = 0.f, hz = 0.f, hn = 0.f;
    for (int k = lane; k < 256; k += 64) {
      float xv = xb[k];
      ir  += xv * w_ih[(size_t)j * 256 + k];
      iz  += xv * w_ih[(size_t)(j + 512) * 256 + k];
      in_ += xv * w_ih[(size_t)(j + 1024) * 256 + k];
    }
    for (int k = lane; k < 512; k += 64) {
      float hv = hb[k];
      hr += hv * w_hh[(size_t)j * 512 + k];
      hz += hv * w_hh[(size_t)(j + 512) * 512 + k];
      hn += hv * w_hh[(size_t)(j + 1024) * 512 + k];
    }
#pragma unroll
    for (int m = 1; m < 64; m <<= 1) {
      ir += __shfl_xor(ir, m, 64); iz += __shfl_xor(iz, m, 64); in_ += __shfl_xor(in_, m, 64);
      hr += __shfl_xor(hr, m, 64); hz += __shfl_xor(hz, m, 64); hn  += __shfl_xor(hn, m, 64);
    }
    if (lane == 0) {
      ir += b_ih[j]; iz += b_ih[j + 512]; in_ += b_ih[j + 1024];
      hr += b_hh[j]; hz += b_hh[j + 512]; hn += b_hh[j + 1024];
      float r = 1.f / (1.f + __expf(-(ir + hr)));
      float z = 1.f / (1.f + __expf(-(iz + hz)));
      float n = tanhf(in_ + r * hn);
      float v = (1.f - z) * n + z * hb[j];
      nh[wid] = v;
      out_nh[wid] = v;
    }
    return;
  }
  // GAT0 projection (FIN=3), transposed outputs
  int gid = (bid - 2064) * 256 + threadIdx.x;
  int grp = gid >> 5, f = gid & 31;          // grp = b*N + n
  int b = grp >> 12, n = grp & 4095;
  const float* v = svp + (size_t)grp * 3;
  float hv = v[0] * W0[f * 3] + v[1] * W0[f * 3 + 1] + v[2] * W0[f * 3 + 2];
  h0t[(size_t)n * 512 + b * 32 + f] = hv;
  float ps = hv * a0s[f], pd = hv * a0d[f];
#pragma unroll
  for (int m = 1; m < 32; m <<= 1) {         // reduce within each 32-lane half
    ps += __shfl_xor(ps, m, 64);
    pd += __shfl_xor(pd, m, 64);
  }
  if (f == 0) { as0t[n * 16 + b] = ps; ad0t[n * 16 + b] = pd; }
}

// ============ L2: padded-CSR direct fill ======================================

__global__ void k_fill2(const int* __restrict__ src, const int* __restrict__ dst,
                        int* __restrict__ cnt, int* __restrict__ csr) {
  int k = blockIdx.x * 256 + threadIdx.x;
  if (k < EE) {
    int d = dst[k];
    int slot = atomicAdd(&cnt[d], 1);
    if ((unsigned)slot < CAP) csr[d * CAP + slot] = src[k];
  }
}

// ============ L3: {agg0 + fused h1-projection | lin1 -> o1b} ==================

__global__ void k_mid(const int* __restrict__ cnt, const int* __restrict__ csr,
                      const float* __restrict__ h0t, const float* __restrict__ as0t,
                      const float* __restrict__ ad0t, const float* __restrict__ b0,
                      const float* __restrict__ W1, const float* __restrict__ a1s,
                      const float* __restrict__ a1d,
                      float* __restrict__ h1t, float* __restrict__ as1t,
                      float* __restrict__ ad1t,
                      const float* __restrict__ nh, const float* __restrict__ l1w,
                      const float* __restrict__ l1b, const float* __restrict__ p1,
                      const float* __restrict__ g1v, const float* __restrict__ be1,
                      ushortT* __restrict__ o1b) {
  const int bid = blockIdx.x;
  const int wave = threadIdx.x >> 6;
  const int lane = threadIdx.x & 63;
  if (bid < 2048) {                   // agg0 + h1 projection: 2 nodes per block
    __shared__ float lds[4][8][36];
    const int n  = bid * 2 + (wave >> 1);
    const int bh = wave & 1;
    const int bl = lane >> 3;
    const int fq = lane & 7;
    const int b  = bh * 8 + bl;
    const int f0 = fq * 4;
    const int boff = b * 32 + f0;
    const int deg = min(cnt[n], CAP);
    const int base = n * CAP;
    const float adn = ad0t[n * 16 + b];
    const int total = deg + 1;        // + self loop
    float4 acc = {0.f, 0.f, 0.f, 0.f};
    float asum = 0.f;
    for (int i = 0; i < total; i += 4) {
      int r0 = csr[base + i];
      int r1 = csr[base + i + 1];
      int r2 = csr[base + i + 2];
      int r3 = csr[base + i + 3];
      int sv0 = (i     < deg) ? r0 : n;
      int sv1 = (i + 1 < deg) ? r1 : n;
      int sv2 = (i + 2 < deg) ? r2 : n;
      int sv3 = (i + 3 < deg) ? r3 : n;
      float e0 = as0t[sv0 * 16 + b];
      float e1 = as0t[sv1 * 16 + b];
      float e2 = as0t[sv2 * 16 + b];
      float e3 = as0t[sv3 * 16 + b];
      float4 hv0 = *(const float4*)(h0t + (size_t)sv0 * 512 + boff);
      float4 hv1 = *(const float4*)(h0t + (size_t)sv1 * 512 + boff);
      float4 hv2 = *(const float4*)(h0t + (size_t)sv2 * 512 + boff);
      float4 hv3 = *(const float4*)(h0t + (size_t)sv3 * 512 + boff);
      float e, w;
      e = e0 + adn; e = e >= 0.f ? e : 0.2f * e;
      w = (i     < total) ? __expf(e) : 0.f;
      asum += w; acc.x += w*hv0.x; acc.y += w*hv0.y; acc.z += w*hv0.z; acc.w += w*hv0.w;
      e = e1 + adn; e = e >= 0.f ? e : 0.2f * e;
      w = (i + 1 < total) ? __expf(e) : 0.f;
      asum += w; acc.x += w*hv1.x; acc.y += w*hv1.y; acc.z += w*hv1.z; acc.w += w*hv1.w;
      e = e2 + adn; e = e >= 0.f ? e : 0.2f * e;
      w = (i + 2 < total) ? __expf(e) : 0.f;
      asum += w; acc.x += w*hv2.x; acc.y += w*hv2.y; acc.z += w*hv2.z; acc.w += w*hv2.w;
      e = e3 + adn; e = e >= 0.f ? e : 0.2f * e;
      w = (i + 3 < total) ? __expf(e) : 0.f;
      asum += w; acc.x += w*hv3.x; acc.y += w*hv3.y; acc.z += w*hv3.z; acc.w += w*hv3.w;
    }
    float inv = 1.f / asum;
    float4 b0v = *(const float4*)(b0 + f0);
    float4 g0;
    g0.x = acc.x * inv + b0v.x; g0.y = acc.y * inv + b0v.y;
    g0.z = acc.z * inv + b0v.z; g0.w = acc.w * inv + b0v.w;
    *(float4*)&lds[wave][bl][f0] = g0;
    __syncthreads();
    float h1a = 0.f, h1b = 0.f, h1c = 0.f, h1d = 0.f;
    const float* gr = lds[wave][bl];
    const float* w1r = W1 + f0 * 32;
#pragma unroll
    for (int k = 0; k < 32; ++k) {
      float gk = gr[k];
      h1a += gk * w1r[k];
      h1b += gk * w1r[32 + k];
      h1c += gk * w1r[64 + k];
      h1d += gk * w1r[96 + k];
    }
    float4 h1v = {h1a, h1b, h1c, h1d};
    *(float4*)(h1t + (size_t)n * 512 + boff) = h1v;
    float ps = h1a * a1s[f0] + h1b * a1s[f0+1] + h1c * a1s[f0+2] + h1d * a1s[f0+3];
    float pd = h1a * a1d[f0] + h1b * a1d[f0+1] + h1c * a1d[f0+2] + h1d * a1d[f0+3];
#pragma unroll
    for (int m = 1; m < 8; m <<= 1) {               // reduce over the 8 fq lanes
      ps += __shfl_xor(ps, m, 64);
      pd += __shfl_xor(pd, m, 64);
    }
    if (fq == 0) { as1t[n * 16 + b] = ps; ad1t[n * 16 + b] = pd; }
    return;
  }
  // lin1: wave per (b,j); output bf16 for the MFMA lin2
  int wid = (bid - 2048) * 4 + wave;
  int b = wid >> 10, j = wid & 1023;
  const float* hb = nh + b * HH;
  const float* wr = l1w + (size_t)j * HH;
  float acc = 0.f;
  for (int k = lane; k < HH; k += 64) acc += hb[k] * wr[k];
#pragma unroll
  for (int m = 1; m < 64; m <<= 1) acc += __shfl_xor(acc, m, 64);
  if (lane == 0) {
    float t = acc + l1b[j];
    t = t >= 0.f ? t : p1[j] * t;
    o1b[wid] = f2b(t * 0.99999500003749973f * g1v[j] + be1[j]);
  }
}

// ============ L4: lin2 via MFMA bf16, f32 weights converted in-register =======
// Wave = one 16-column output tile (16 batches x 16 cols), K=1024 in 32 MFMA.
// A-frag: o1b (bf16, 32 KB, L1/L2-hot). B-frag: l2w f32 loaded as 2x float4,
// converted to 8 bf16 in registers per MFMA.
// C/D per m89: col=lane&15 (output col j), row=(lane>>4)*4+reg (batch).

__global__ __launch_bounds__(256) void k_lin2m(
    const ushortT* __restrict__ o1b, const float* __restrict__ l2w,
    const float* __restrict__ bias, const float* __restrict__ pr,
    const float* __restrict__ g, const float* __restrict__ be,
    float* __restrict__ o2) {
  const int wave = threadIdx.x >> 6;
  const int lane = threadIdx.x & 63;
  const int r16 = lane & 15;
  const int chunk = lane >> 4;
  const int j0 = (blockIdx.x * 4 + wave) * 16;
  const s8v* ap = (const s8v*)(o1b + r16 * 1024 + chunk * 8);
  const float4* bp = (const float4*)(l2w + (size_t)(j0 + r16) * 1024 + chunk * 8);
  f4v acc = {0.f, 0.f, 0.f, 0.f};
#pragma unroll 4
  for (int it = 0; it < 32; ++it) {
    s8v a = ap[it * 4];               // advance 32 bf16 per iter
    float4 w0 = bp[it * 8];           // advance 32 floats per iter
    float4 w1 = bp[it * 8 + 1];
    s8v b;
    b[0] = (short)f2b(w0.x); b[1] = (short)f2b(w0.y);
    b[2] = (short)f2b(w0.z); b[3] = (short)f2b(w0.w);
    b[4] = (short)f2b(w1.x); b[5] = (short)f2b(w1.y);
    b[6] = (short)f2b(w1.z); b[7] = (short)f2b(w1.w);
    acc = __builtin_amdgcn_mfma_f32_16x16x32_bf16(a, b, acc, 0, 0, 0);
  }
  const int j = j0 + r16;
  const float bj = bias[j], pj = pr[j], gj = g[j], bej = be[j];
  const float INV = 0.99999500003749973f;
#pragma unroll
  for (int r = 0; r < 4; ++r) {
    int b = chunk * 4 + r;            // batch row
    float t = acc[r] + bj;
    t = t >= 0.f ? t : pj * t;
    o2[(size_t)b * M2N + j] = t * INV * gj + bej;
  }
}

// ============ L5: agg1 + fused output projection ==============================

__global__ void k_fin(const int* __restrict__ cnt, const int* __restrict__ csr,
                      const float* __restrict__ h1t, const float* __restrict__ as1t,
                      const float* __restrict__ ad1t, const float* __restrict__ b1,
                      const float* __restrict__ o2, const float* __restrict__ wout,
                      const float* __restrict__ bout, float* __restrict__ y) {
  const int wave = threadIdx.x >> 6;
  const int lane = threadIdx.x & 63;
  const int n  = blockIdx.x * 2 + (wave >> 1);
  const int bh = wave & 1;
  const int bl = lane >> 3;
  const int fq = lane & 7;
  const int b  = bh * 8 + bl;
  const int f0 = fq * 4;
  const int boff = b * 32 + f0;
  const int deg = min(cnt[n], CAP);
  const int base = n * CAP;
  const float adn = ad1t[n * 16 + b];
  const int total = deg + 1;
  float4 acc = {0.f, 0.f, 0.f, 0.f};
  float asum = 0.f;
  for (int i = 0; i < total; i += 4) {
    int r0 = csr[base + i];
    int r1 = csr[base + i + 1];
    int r2 = csr[base + i + 2];
    int r3 = csr[base + i + 3];
    int sv0 = (i     < deg) ? r0 : n;
    int sv1 = (i + 1 < deg) ? r1 : n;
    int sv2 = (i + 2 < deg) ? r2 : n;
    int sv3 = (i + 3 < deg) ? r3 : n;
    float e0 = as1t[sv0 * 16 + b];
    float e1 = as1t[sv1 * 16 + b];
    float e2 = as1t[sv2 * 16 + b];
    float e3 = as1t[sv3 * 16 + b];
    float4 hv0 = *(const float4*)(h1t + (size_t)sv0 * 512 + boff);
    float4 hv1 = *(const float4*)(h1t + (size_t)sv1 * 512 + boff);
    float4 hv2 = *(const float4*)(h1t + (size_t)sv2 * 512 + boff);
    float4 hv3 = *(const float4*)(h1t + (size_t)sv3 * 512 + boff);
    float e, w;
    e = e0 + adn; e = e >= 0.f ? e : 0.2f * e;
    w = (i     < total) ? __expf(e) : 0.f;
    asum += w; acc.x += w*hv0.x; acc.y += w*hv0.y; acc.z += w*hv0.z; acc.w += w*hv0.w;
    e = e1 + adn; e = e >= 0.f ? e : 0.2f * e;
    w = (i + 1 < total) ? __expf(e) : 0.f;
    asum += w; acc.x += w*hv1.x; acc.y += w*hv1.y; acc.z += w*hv1.z; acc.w += w*hv1.w;
    e = e2 + adn; e = e >= 0.f ? e : 0.2f * e;
    w = (i + 2 < total) ? __expf(e) : 0.f;
    asum += w; acc.x += w*hv2.x; acc.y += w*hv2.y; acc.z += w*hv2.z; acc.w += w*hv2.w;
    e = e3 + adn; e = e >= 0.f ? e : 0.2f * e;
    w = (i + 3 < total) ? __expf(e) : 0.f;
    asum += w; acc.x += w*hv3.x; acc.y += w*hv3.y; acc.z += w*hv3.z; acc.w += w*hv3.w;
  }
  float inv = 1.f / asum;
  float4 b1v = *(const float4*)(b1 + f0);
  float gx = acc.x * inv + b1v.x, gy = acc.y * inv + b1v.y;
  float gz = acc.z * inv + b1v.z, gw = acc.w * inv + b1v.w;
  float pc0 = gx*wout[ 8+f0] + gy*wout[ 9+f0] + gz*wout[10+f0] + gw*wout[11+f0];
  float pc1 = gx*wout[48+f0] + gy*wout[49+f0] + gz*wout[50+f0] + gw*wout[51+f0];
  float pc2 = gx*wout[88+f0] + gy*wout[89+f0] + gz*wout[90+f0] + gw*wout[91+f0];
#pragma unroll
  for (int m = 1; m < 8; m <<= 1) {
    pc0 += __shfl_xor(pc0, m, 64);
    pc1 += __shfl_xor(pc1, m, 64);
    pc2 += __shfl_xor(pc2, m, 64);
  }
  if (fq == 0) {
    const float* gr = o2 + (size_t)b * M2N + n * 8;
    float4 ga = *(const float4*)gr;
    float4 gb = *(const float4*)(gr + 4);
    float c0 = pc0 + bout[0], c1 = pc1 + bout[1], c2 = pc2 + bout[2];
    c0 += ga.x*wout[0]  + ga.y*wout[1]  + ga.z*wout[2]  + ga.w*wout[3]
        + gb.x*wout[4]  + gb.y*wout[5]  + gb.z*wout[6]  + gb.w*wout[7];
    c1 += ga.x*wout[40] + ga.y*wout[41] + ga.z*wout[42] + ga.w*wout[43]
        + gb.x*wout[44] + gb.y*wout[45] + gb.z*wout[46] + gb.w*wout[47];
    c2 += ga.x*wout[80] + ga.y*wout[81] + ga.z*wout[82] + ga.w*wout[83]
        + gb.x*wout[84] + gb.y*wout[85] + gb.z*wout[86] + gb.w*wout[87];
    float* yp = y + (size_t)b * (NN * 3) + n * 3;
    yp[0] = c0; yp[1] = c1; yp[2] = c2;
  }
}

// ------------------------------------------------------------------------------

extern "C" void kernel_launch(void* const* d_in, const int* in_sizes, int n_in,
                              void* d_out, int out_size, void* d_ws, size_t ws_size,
                              hipStream_t stream) {
  const float* x    = (const float*)d_in[0];
  const float* svp  = (const float*)d_in[1];
  const float* hid  = (const float*)d_in[2];
  const int*   ei   = (const int*)d_in[3];
  const float* W0   = (const float*)d_in[4];
  const float* a0s  = (const float*)d_in[5];
  const float* a0d  = (const float*)d_in[6];
  const float* b0   = (const float*)d_in[7];
  const float* W1   = (const float*)d_in[8];
  const float* a1s  = (const float*)d_in[9];
  const float* a1d  = (const float*)d_in[10];
  const float* b1   = (const float*)d_in[11];
  const float* w_ih = (const float*)d_in[12];
  const float* w_hh = (const float*)d_in[13];
  const float* b_ih = (const float*)d_in[14];
  const float* b_hh = (const float*)d_in[15];
  const float* l1w  = (const float*)d_in[16];
  const float* l1b  = (const float*)d_in[17];
  const float* p1   = (const float*)d_in[18];
  const float* g1v  = (const float*)d_in[19];
  const float* be1  = (const float*)d_in[20];
  const float* l2w  = (const float*)d_in[21];
  const float* l2b  = (const float*)d_in[22];
  const float* p2   = (const float*)d_in[23];
  const float* g2v  = (const float*)d_in[24];
  const float* be2  = (const float*)d_in[25];
  const float* wout = (const float*)d_in[26];
  const float* bout = (const float*)d_in[27];
  float* out = (float*)d_out;

  char* ws = (char*)d_ws;
  size_t off = 0;
  auto alloc = [&](size_t bytes) -> char* {
    char* p = ws + off;
    off += (bytes + 255) & ~(size_t)255;
    return p;
  };
  int*     cnt   = (int*)alloc((size_t)NN * 4);
  int*     csr   = (int*)alloc(((size_t)NN * CAP + 16) * 4);  // +16 pad
  float*   h0t   = (float*)alloc((size_t)NN * 16 * 32 * 4);
  float*   as0t  = (float*)alloc((size_t)NN * 16 * 4);
  float*   ad0t  = (float*)alloc((size_t)NN * 16 * 4);
  float*   h1t   = (float*)alloc((size_t)NN * 16 * 32 * 4);
  float*   as1t  = (float*)alloc((size_t)NN * 16 * 4);
  float*   ad1t  = (float*)alloc((size_t)NN * 16 * 4);
  float*   nh    = (float*)alloc((size_t)BB * HH * 4);
  ushortT* o1b   = (ushortT*)alloc((size_t)BB * M1N * 2);
  float*   o2    = (float*)alloc((size_t)BB * M2N * 4);

  const int* srcv = ei;
  const int* dstv = ei + EE;

  k_pre<<<16 + 2048 + 8192, 256, 0, stream>>>(
      cnt, x, hid, w_ih, w_hh, b_ih, b_hh, nh, out + (size_t)BB * NN * 3,
      svp, W0, a0s, a0d, h0t, as0t, ad0t);
  k_fill2<<<EE / 256, 256, 0, stream>>>(srcv, dstv, cnt, csr);
  k_mid<<<2048 + 4096, 256, 0, stream>>>(
      cnt, csr, h0t, as0t, ad0t, b0, W1, a1s, a1d, h1t, as1t, ad1t,
      nh, l1w, l1b, p1, g1v, be1, o1b);
  k_lin2m<<<M2N / 64, 256, 0, stream>>>(o1b, l2w, l2b, p2, g2v, be2, o2);
  k_fin<<<2048, 256, 0, stream>>>(cnt, csr, h1t, as1t, ad1t, b1, o2, wout, bout, out);
}